// Round 1
// baseline (675.544 us; speedup 1.0000x reference)
//
#include <hip/hip_runtime.h>

#define N_TOT 8192
#define BHALF 4096
#define D 512
#define C 31
#define TILE 128
#define KB 16

// workspace float offsets
#define SQ_OFF   0          // 8192 floats
#define CV_OFF   8192       // 8192*32 floats
#define M_OFF    270336     // 512 floats (column sums)
#define SVAL_OFF 270848     // 31 (+pad)
#define TSC_OFF  270880     // 31 (+pad)
#define SCAL_OFF 270912     // [0]=neg_inv_bw [1]=inv_len
#define TSUM_OFF 270944     // 31 (+pad)
#define PRES_OFF 270976     // 31 ints (+pad)
#define WS_FLOATS 271008

__device__ __forceinline__ const float* row_ptr(const float* s, const float* t, int row) {
  return (row < BHALF) ? (s + (size_t)row * D) : (t + (size_t)(row - BHALF) * D);
}

// one wave per row: sum of squares
__global__ __launch_bounds__(256) void k_row_sq(const float* __restrict__ src,
                                                const float* __restrict__ tgt,
                                                float* __restrict__ sq) {
  int wid = threadIdx.x >> 6, lane = threadIdx.x & 63;
  int row = blockIdx.x * 4 + wid;
  const float* p = row_ptr(src, tgt, row);
  float4 v0 = *(const float4*)(p + lane * 8);
  float4 v1 = *(const float4*)(p + lane * 8 + 4);
  float s = v0.x*v0.x + v0.y*v0.y + v0.z*v0.z + v0.w*v0.w
          + v1.x*v1.x + v1.y*v1.y + v1.z*v1.z + v1.w*v1.w;
  #pragma unroll
  for (int off = 32; off; off >>= 1) s += __shfl_xor(s, off);
  if (lane == 0) sq[row] = s;
}

// column sums of total (for closed-form sum(L2))
__global__ __launch_bounds__(256) void k_colsum(const float* __restrict__ src,
                                                const float* __restrict__ tgt,
                                                float* __restrict__ m) {
  const float* p = (blockIdx.x < 32) ? (src + (size_t)blockIdx.x * 128 * D)
                                     : (tgt + (size_t)(blockIdx.x - 32) * 128 * D);
  int c1 = threadIdx.x, c2 = threadIdx.x + 256;
  float a1 = 0.f, a2 = 0.f;
  for (int r = 0; r < 128; r++) {
    a1 += p[(size_t)r * D + c1];
    a2 += p[(size_t)r * D + c2];
  }
  atomicAdd(&m[c1], a1);
  atomicAdd(&m[c2], a2);
}

// t_label column sums + argmax presence
__global__ __launch_bounds__(256) void k_tstats(const float* __restrict__ tl,
                                                float* __restrict__ tsum,
                                                int* __restrict__ pres) {
  __shared__ float ts[C];
  if (threadIdx.x < C) ts[threadIdx.x] = 0.f;
  __syncthreads();
  int base = blockIdx.x * 128 * C;
  for (int idx = threadIdx.x; idx < 128 * C; idx += 256) {
    int g = base + idx;
    atomicAdd(&ts[idx % C], tl[g]);
  }
  if (threadIdx.x < 128) {
    int row = blockIdx.x * 128 + threadIdx.x;
    const float* p = tl + (size_t)row * C;
    float best = p[0]; int bi = 0;
    for (int c = 1; c < C; c++) { float v = p[c]; if (v > best) { best = v; bi = c; } }
    pres[bi] = 1;
  }
  __syncthreads();
  if (threadIdx.x < C) atomicAdd(&tsum[threadIdx.x], ts[threadIdx.x]);
}

// single block: bandwidth scalar + class masks/scales
__global__ __launch_bounds__(256) void k_prep(const float* __restrict__ sq,
                                              const float* __restrict__ m,
                                              const int* __restrict__ slab,
                                              const float* __restrict__ tsum,
                                              const int* __restrict__ pres,
                                              float* __restrict__ sval,
                                              float* __restrict__ tscale,
                                              float* __restrict__ scal) {
  __shared__ float red[4];
  __shared__ int cnt[C];
  __shared__ float Ssh, Msh;
  int tid = threadIdx.x;
  if (tid < C) cnt[tid] = 0;
  float s = 0.f;
  for (int i = tid; i < N_TOT; i += 256) s += sq[i];
  #pragma unroll
  for (int off = 32; off; off >>= 1) s += __shfl_xor(s, off);
  if ((tid & 63) == 0) red[tid >> 6] = s;
  __syncthreads();
  if (tid == 0) Ssh = red[0] + red[1] + red[2] + red[3];
  __syncthreads();
  float q = 0.f;
  for (int d = tid; d < D; d += 256) q += m[d] * m[d];
  #pragma unroll
  for (int off = 32; off; off >>= 1) q += __shfl_xor(q, off);
  if ((tid & 63) == 0) red[tid >> 6] = q;
  __syncthreads();
  if (tid == 0) Msh = red[0] + red[1] + red[2] + red[3];
  for (int i = tid; i < BHALF; i += 256) atomicAdd(&cnt[slab[i]], 1);
  __syncthreads();
  if (tid == 0) {
    double S = (double)Ssh, M2 = (double)Msh;
    double sumL2 = 2.0 * (double)N_TOT * S - 2.0 * M2;
    double bw = sumL2 / ((double)N_TOT * (double)N_TOT - (double)N_TOT) / 4.0;
    scal[0] = (float)(-1.0 / bw);
    int len = 0;
    for (int c = 0; c < C; c++) {
      int mk = (cnt[c] > 0 && pres[c] != 0) ? 1 : 0;
      len += mk;
      sval[c] = mk ? (1.0f / (float)cnt[c]) : 0.0f;
      float tv = tsum[c];
      tscale[c] = mk ? (1.0f / (tv == 0.0f ? 1.0f : tv)) : 0.0f;
    }
    scal[1] = (len > 0) ? (1.0f / (float)len) : 0.0f;
  }
}

// signed weight vectors: +s_vec for source rows, -t_vec for target rows
__global__ __launch_bounds__(256) void k_cvec(const int* __restrict__ slab,
                                              const float* __restrict__ tl,
                                              const float* __restrict__ sval,
                                              const float* __restrict__ tscale,
                                              float* __restrict__ cvec) {
  int row = blockIdx.x * 256 + threadIdx.x;
  float* o = cvec + (size_t)row * 32;
  if (row < BHALF) {
    int c = slab[row];
    #pragma unroll
    for (int cc = 0; cc < 32; cc++) o[cc] = 0.f;
    o[c] = sval[c];
  } else {
    const float* p = tl + (size_t)(row - BHALF) * C;
    for (int cc = 0; cc < C; cc++) o[cc] = -p[cc] * tscale[cc];
    o[C] = 0.f;
  }
}

// fused: distance GEMM tile + 5-scale gaussian + weight contraction
__global__ __launch_bounds__(256) void k_main(const float* __restrict__ src,
                                              const float* __restrict__ tgt,
                                              const float* __restrict__ sq,
                                              const float* __restrict__ cvec,
                                              const float* __restrict__ scal,
                                              float* __restrict__ out) {
  int ti = blockIdx.y, tj = blockIdx.x;
  if (tj < ti) return;  // symmetric: upper-triangle tiles only
  __shared__ float As[KB][TILE + 4];
  __shared__ float Bs[KB][TILE + 4];
  __shared__ float ca[TILE][33];
  __shared__ float cb[TILE][33];
  __shared__ float sqa[TILE];
  __shared__ float sqb[TILE];
  __shared__ float red[4];
  int tid = threadIdx.x;
  int i0 = ti * TILE, j0 = tj * TILE;
  for (int idx = tid; idx < TILE * 32; idx += 256) {
    int r = idx >> 5, c = idx & 31;
    ca[r][c] = cvec[(size_t)(i0 + r) * 32 + c];
    cb[r][c] = cvec[(size_t)(j0 + r) * 32 + c];
  }
  if (tid < TILE) { sqa[tid] = sq[i0 + tid]; sqb[tid] = sq[j0 + tid]; }
  float acc[8][8];
  #pragma unroll
  for (int r = 0; r < 8; r++)
    #pragma unroll
    for (int c = 0; c < 8; c++) acc[r][c] = 0.f;
  int ty = tid >> 4, tx = tid & 15;
  for (int kc = 0; kc < D; kc += KB) {
    __syncthreads();
    #pragma unroll
    for (int rep = 0; rep < 2; rep++) {
      int lin = tid + rep * 256;
      int r = lin >> 2, kq = (lin & 3) * 4;
      const float* pa = row_ptr(src, tgt, i0 + r);
      float4 va = *(const float4*)(pa + kc + kq);
      As[kq + 0][r] = va.x; As[kq + 1][r] = va.y; As[kq + 2][r] = va.z; As[kq + 3][r] = va.w;
      const float* pb = row_ptr(src, tgt, j0 + r);
      float4 vb = *(const float4*)(pb + kc + kq);
      Bs[kq + 0][r] = vb.x; Bs[kq + 1][r] = vb.y; Bs[kq + 2][r] = vb.z; Bs[kq + 3][r] = vb.w;
    }
    __syncthreads();
    #pragma unroll
    for (int k = 0; k < KB; k++) {
      float4 a0 = *(const float4*)&As[k][ty * 8];
      float4 a1 = *(const float4*)&As[k][ty * 8 + 4];
      float4 b0 = *(const float4*)&Bs[k][tx * 8];
      float4 b1 = *(const float4*)&Bs[k][tx * 8 + 4];
      float av[8] = {a0.x, a0.y, a0.z, a0.w, a1.x, a1.y, a1.z, a1.w};
      float bv[8] = {b0.x, b0.y, b0.z, b0.w, b1.x, b1.y, b1.z, b1.w};
      #pragma unroll
      for (int r = 0; r < 8; r++)
        #pragma unroll
        for (int c = 0; c < 8; c++)
          acc[r][c] = fmaf(av[r], bv[c], acc[r][c]);
    }
  }
  float nib = scal[0];
  float invlen = scal[1];
  #pragma unroll
  for (int r = 0; r < 8; r++) {
    float sa = sqa[ty * 8 + r];
    #pragma unroll
    for (int c = 0; c < 8; c++) {
      float l2 = fmaxf(sa + sqb[tx * 8 + c] - 2.0f * acc[r][c], 0.0f);
      float g = l2 * nib;  // <= 0
      acc[r][c] = __expf(g) + __expf(g * 0.5f) + __expf(g * 0.25f)
                + __expf(g * 0.125f) + __expf(g * 0.0625f);
    }
  }
  float partial = 0.f;
  for (int c = 0; c < C; c++) {
    float la[8], lb[8];
    #pragma unroll
    for (int r = 0; r < 8; r++) la[r] = ca[ty * 8 + r][c];
    #pragma unroll
    for (int j = 0; j < 8; j++) lb[j] = cb[tx * 8 + j][c];
    #pragma unroll
    for (int j = 0; j < 8; j++) {
      float t = 0.f;
      #pragma unroll
      for (int r = 0; r < 8; r++) t = fmaf(la[r], acc[r][j], t);
      partial = fmaf(t, lb[j], partial);
    }
  }
  #pragma unroll
  for (int off = 32; off; off >>= 1) partial += __shfl_xor(partial, off);
  if ((tid & 63) == 0) red[tid >> 6] = partial;
  __syncthreads();
  if (tid == 0) {
    float v = (red[0] + red[1] + red[2] + red[3]) * invlen * ((ti == tj) ? 1.0f : 2.0f);
    atomicAdd(out, v);
  }
}

extern "C" void kernel_launch(void* const* d_in, const int* in_sizes, int n_in,
                              void* d_out, int out_size, void* d_ws, size_t ws_size,
                              hipStream_t stream) {
  const float* src = (const float*)d_in[0];
  const float* tgt = (const float*)d_in[1];
  const int* slab  = (const int*)d_in[2];
  const float* tl  = (const float*)d_in[3];
  float* ws = (float*)d_ws;
  float* out = (float*)d_out;
  float* sq     = ws + SQ_OFF;
  float* cvec   = ws + CV_OFF;
  float* m      = ws + M_OFF;
  float* sval   = ws + SVAL_OFF;
  float* tscale = ws + TSC_OFF;
  float* scal   = ws + SCAL_OFF;
  float* tsum   = ws + TSUM_OFF;
  int*   pres   = (int*)(ws + PRES_OFF);
  hipMemsetAsync(out, 0, sizeof(float), stream);
  hipMemsetAsync(m, 0, (WS_FLOATS - M_OFF) * sizeof(float), stream);
  hipLaunchKernelGGL(k_row_sq, dim3(2048), dim3(256), 0, stream, src, tgt, sq);
  hipLaunchKernelGGL(k_colsum, dim3(64), dim3(256), 0, stream, src, tgt, m);
  hipLaunchKernelGGL(k_tstats, dim3(32), dim3(256), 0, stream, tl, tsum, pres);
  hipLaunchKernelGGL(k_prep, dim3(1), dim3(256), 0, stream, sq, m, slab, tsum, pres, sval, tscale, scal);
  hipLaunchKernelGGL(k_cvec, dim3(32), dim3(256), 0, stream, slab, tl, sval, tscale, cvec);
  hipLaunchKernelGGL(k_main, dim3(64, 64), dim3(256), 0, stream, src, tgt, sq, cvec, scal, out);
}

// Round 2
// 184.104 us; speedup vs baseline: 3.6694x; 3.6694x over previous
//
#include <hip/hip_runtime.h>

#define N_TOT 8192
#define BHALF 4096
#define D 512
#define C 31

typedef float f32x16 __attribute__((ext_vector_type(16)));
typedef __bf16 bf16x8 __attribute__((ext_vector_type(8)));

// ---------------- helpers ----------------
__device__ __forceinline__ uint bf16_rne(uint u) {
  return (u + 0x7fffu + ((u >> 16) & 1u)) >> 16;
}
__device__ __forceinline__ void split2(float x, uint& h, uint& lo) {
  uint u = __float_as_uint(x);
  h = bf16_rne(u);
  float hf = __uint_as_float(h << 16);
  lo = bf16_rne(__float_as_uint(x - hf));
}
__device__ __forceinline__ void gll16(const ushort* g, ushort* s) {
  __builtin_amdgcn_global_load_lds(
      (const __attribute__((address_space(1))) unsigned int*)g,
      (__attribute__((address_space(3))) unsigned int*)s, 16, 0, 0);
}

// one-time: split concat(source,target) into hi/lo bf16, fragment-tiled layout
// layout: [rg32 = row>>5][ks = k>>4][lane = (row&31)+32*((k>>3)&1)][j = k&7] ushort
__global__ __launch_bounds__(256) void k_split(const float* __restrict__ src,
                                               const float* __restrict__ tgt,
                                               ushort* __restrict__ hiG,
                                               ushort* __restrict__ loG) {
  int lin = blockIdx.x * 256 + threadIdx.x;  // 1M threads, one float4 each
  int row = lin >> 7;
  int kq = (lin & 127) << 2;
  const float* p = (row < BHALF) ? src + (size_t)row * D : tgt + (size_t)(row - BHALF) * D;
  float4 v = *(const float4*)(p + kq);
  uint h0,l0,h1,l1,h2,l2,h3,l3;
  split2(v.x,h0,l0); split2(v.y,h1,l1); split2(v.z,h2,l2); split2(v.w,h3,l3);
  int rg = row >> 5;
  int ks = kq >> 4;
  int lane = (row & 31) + (((kq >> 3) & 1) << 5);
  int j0 = kq & 7;  // 0 or 4
  size_t idx = (((size_t)rg * 32 + ks) * 64 + lane) * 8 + j0;
  *(uint2*)(hiG + idx) = make_uint2(h0 | (h1 << 16), h2 | (h3 << 16));
  *(uint2*)(loG + idx) = make_uint2(l0 | (l1 << 16), l2 | (l3 << 16));
}

// one wave per row: sum of squares
__global__ __launch_bounds__(256) void k_row_sq(const float* __restrict__ src,
                                                const float* __restrict__ tgt,
                                                float* __restrict__ sq) {
  int wid = threadIdx.x >> 6, lane = threadIdx.x & 63;
  int row = blockIdx.x * 4 + wid;
  const float* p = (row < BHALF) ? src + (size_t)row * D : tgt + (size_t)(row - BHALF) * D;
  float4 v0 = *(const float4*)(p + lane * 8);
  float4 v1 = *(const float4*)(p + lane * 8 + 4);
  float s = v0.x*v0.x + v0.y*v0.y + v0.z*v0.z + v0.w*v0.w
          + v1.x*v1.x + v1.y*v1.y + v1.z*v1.z + v1.w*v1.w;
  #pragma unroll
  for (int off = 32; off; off >>= 1) s += __shfl_xor(s, off);
  if (lane == 0) sq[row] = s;
}

// column sums (for closed-form sum(L2))
__global__ __launch_bounds__(256) void k_colsum(const float* __restrict__ src,
                                                const float* __restrict__ tgt,
                                                float* __restrict__ m) {
  const float* p = (blockIdx.x < 32) ? (src + (size_t)blockIdx.x * 128 * D)
                                     : (tgt + (size_t)(blockIdx.x - 32) * 128 * D);
  int c1 = threadIdx.x, c2 = threadIdx.x + 256;
  float a1 = 0.f, a2 = 0.f;
  for (int r = 0; r < 128; r++) {
    a1 += p[(size_t)r * D + c1];
    a2 += p[(size_t)r * D + c2];
  }
  atomicAdd(&m[c1], a1);
  atomicAdd(&m[c2], a2);
}

// t_label column sums + argmax presence
__global__ __launch_bounds__(256) void k_tstats(const float* __restrict__ tl,
                                                float* __restrict__ tsum,
                                                int* __restrict__ pres) {
  __shared__ float ts[C];
  if (threadIdx.x < C) ts[threadIdx.x] = 0.f;
  __syncthreads();
  int base = blockIdx.x * 128 * C;
  for (int idx = threadIdx.x; idx < 128 * C; idx += 256) {
    atomicAdd(&ts[idx % C], tl[base + idx]);
  }
  if (threadIdx.x < 128) {
    int row = blockIdx.x * 128 + threadIdx.x;
    const float* p = tl + (size_t)row * C;
    float best = p[0]; int bi = 0;
    for (int c = 1; c < C; c++) { float v = p[c]; if (v > best) { best = v; bi = c; } }
    pres[bi] = 1;
  }
  __syncthreads();
  if (threadIdx.x < C) atomicAdd(&tsum[threadIdx.x], ts[threadIdx.x]);
}

// single block: bandwidth scalar + class masks/scales
__global__ __launch_bounds__(256) void k_prep(const float* __restrict__ sq,
                                              const float* __restrict__ m,
                                              const int* __restrict__ slab,
                                              const float* __restrict__ tsum,
                                              const int* __restrict__ pres,
                                              float* __restrict__ sval,
                                              float* __restrict__ tscale,
                                              float* __restrict__ scal) {
  __shared__ float red[4];
  __shared__ int cnt[C];
  __shared__ float Ssh, Msh;
  int tid = threadIdx.x;
  if (tid < C) cnt[tid] = 0;
  float s = 0.f;
  for (int i = tid; i < N_TOT; i += 256) s += sq[i];
  #pragma unroll
  for (int off = 32; off; off >>= 1) s += __shfl_xor(s, off);
  if ((tid & 63) == 0) red[tid >> 6] = s;
  __syncthreads();
  if (tid == 0) Ssh = red[0] + red[1] + red[2] + red[3];
  __syncthreads();
  float q = 0.f;
  for (int d = tid; d < D; d += 256) q += m[d] * m[d];
  #pragma unroll
  for (int off = 32; off; off >>= 1) q += __shfl_xor(q, off);
  if ((tid & 63) == 0) red[tid >> 6] = q;
  __syncthreads();
  if (tid == 0) Msh = red[0] + red[1] + red[2] + red[3];
  for (int i = tid; i < BHALF; i += 256) atomicAdd(&cnt[slab[i]], 1);
  __syncthreads();
  if (tid == 0) {
    double S = (double)Ssh, M2 = (double)Msh;
    double sumL2 = 2.0 * (double)N_TOT * S - 2.0 * M2;
    double bw = sumL2 / ((double)N_TOT * (double)N_TOT - (double)N_TOT) / 4.0;
    scal[0] = (float)(-1.0 / bw);
    int len = 0;
    for (int c = 0; c < C; c++) {
      int mk = (cnt[c] > 0 && pres[c] != 0) ? 1 : 0;
      len += mk;
      sval[c] = mk ? (1.0f / (float)cnt[c]) : 0.0f;
      float tv = tsum[c];
      tscale[c] = mk ? (1.0f / (tv == 0.0f ? 1.0f : tv)) : 0.0f;
    }
    scal[1] = (len > 0) ? (1.0f / (float)len) : 0.0f;
  }
}

// signed weight vectors -> split hi/lo, fragment-tiled layout (K=32 classes)
// layout: [rg32 = row>>5][ks = cls>>4][lane = (row&31)+32*((cls>>3)&1)][j = cls&7]
__global__ __launch_bounds__(256) void k_cvec(const int* __restrict__ slab,
                                              const float* __restrict__ tl,
                                              const float* __restrict__ sval,
                                              const float* __restrict__ tscale,
                                              ushort* __restrict__ cH,
                                              ushort* __restrict__ cL) {
  int row = blockIdx.x * 256 + threadIdx.x;
  float c[32];
  if (row < BHALF) {
    int cls = slab[row];
    float v = sval[cls];
    #pragma unroll
    for (int i = 0; i < 32; ++i) c[i] = (i == cls) ? v : 0.f;
  } else {
    const float* p = tl + (size_t)(row - BHALF) * C;
    #pragma unroll
    for (int i = 0; i < C; ++i) c[i] = -p[i] * tscale[i];
    c[C] = 0.f;
  }
  int rg = row >> 5;
  #pragma unroll
  for (int ks = 0; ks < 2; ++ks)
    #pragma unroll
    for (int hf = 0; hf < 2; ++hf) {
      int lane = (row & 31) + (hf << 5);
      size_t base = (((size_t)rg * 2 + ks) * 64 + lane) * 8;
      uint h[8], lo[8];
      #pragma unroll
      for (int j = 0; j < 8; ++j) split2(c[ks * 16 + hf * 8 + j], h[j], lo[j]);
      *(uint2*)(cH + base)     = make_uint2(h[0]|(h[1]<<16),  h[2]|(h[3]<<16));
      *(uint2*)(cH + base + 4) = make_uint2(h[4]|(h[5]<<16),  h[6]|(h[7]<<16));
      *(uint2*)(cL + base)     = make_uint2(lo[0]|(lo[1]<<16), lo[2]|(lo[3]<<16));
      *(uint2*)(cL + base + 4) = make_uint2(lo[4]|(lo[5]<<16), lo[6]|(lo[7]<<16));
    }
}

// main: split-bf16 MFMA distance GEMM + gaussian + MFMA weight tile + contraction
__global__ __launch_bounds__(256, 2) void k_main(
    const ushort* __restrict__ hiG, const ushort* __restrict__ loG,
    const ushort* __restrict__ cH, const ushort* __restrict__ cL,
    const float* __restrict__ sq, const float* __restrict__ scal,
    float* __restrict__ out) {
  __shared__ ushort As[2][4096];  // [hi/lo][((rg*2+ks)*64+lane)*8]
  __shared__ ushort Bs[2][4096];
  __shared__ float sqA[128], sqB[128], red[4];

  int tid = threadIdx.x;
  int l = tid & 63, wid = tid >> 6;

  // decode upper-triangle tile index
  int ti = 0, rem = blockIdx.x;
  for (;;) { int w = 64 - ti; if (rem < w) break; rem -= w; ++ti; }
  int tj = ti + rem;
  int i0 = ti * 128, j0 = tj * 128;

  if (tid < 128) { sqA[tid] = sq[i0 + tid]; sqB[tid] = sq[j0 + tid]; }

  f32x16 zero16;
  #pragma unroll
  for (int k = 0; k < 16; ++k) zero16[k] = 0.f;
  f32x16 acc[2][2];
  acc[0][0] = zero16; acc[0][1] = zero16; acc[1][0] = zero16; acc[1][1] = zero16;

  int wrg = (wid >> 1) * 2;  // wave's local rg32 base (A side)
  int wcg = (wid & 1) * 2;   // wave's local rg32 base (B side)

  // wave staging role: wid0->A_hi, wid1->A_lo, wid2->B_hi, wid3->B_lo
  ushort* lbuf = (wid < 2) ? As[wid & 1] : Bs[wid & 1];
  const ushort* gbuf = (wid & 1) ? loG : hiG;
  int rgbase = (wid < 2) ? ti * 4 : tj * 4;

  for (int kci = 0; kci < 16; ++kci) {
    __syncthreads();
    #pragma unroll
    for (int r = 0; r < 8; ++r) {
      int rg = r >> 1, ks = r & 1;
      const ushort* g = gbuf + ((((size_t)(rgbase + rg) * 32) + kci * 2 + ks) * 64 + l) * 8;
      ushort* s = lbuf + ((rg * 2 + ks) * 64 + l) * 8;
      gll16(g, s);
    }
    __syncthreads();
    bf16x8 aH[2][2], aL[2][2], bH[2][2], bL[2][2];
    #pragma unroll
    for (int rg = 0; rg < 2; ++rg)
      #pragma unroll
      for (int ks = 0; ks < 2; ++ks) {
        int o = (((wrg + rg) * 2 + ks) * 64 + l) * 8;
        aH[rg][ks] = *(const bf16x8*)(As[0] + o);
        aL[rg][ks] = *(const bf16x8*)(As[1] + o);
        int o2 = (((wcg + rg) * 2 + ks) * 64 + l) * 8;
        bH[rg][ks] = *(const bf16x8*)(Bs[0] + o2);
        bL[rg][ks] = *(const bf16x8*)(Bs[1] + o2);
      }
    #pragma unroll
    for (int i = 0; i < 2; ++i)
      #pragma unroll
      for (int j = 0; j < 2; ++j)
        #pragma unroll
        for (int ks = 0; ks < 2; ++ks) {
          acc[i][j] = __builtin_amdgcn_mfma_f32_32x32x16_bf16(aH[i][ks], bH[j][ks], acc[i][j], 0, 0, 0);
          acc[i][j] = __builtin_amdgcn_mfma_f32_32x32x16_bf16(aH[i][ks], bL[j][ks], acc[i][j], 0, 0, 0);
          acc[i][j] = __builtin_amdgcn_mfma_f32_32x32x16_bf16(aL[i][ks], bH[j][ks], acc[i][j], 0, 0, 0);
        }
  }

  // weight tile W = Ca . Cb^T  (K=32 classes), same split-bf16 trick
  __syncthreads();
  {
    const ushort* gc = (wid & 1) ? cL : cH;
    #pragma unroll
    for (int r = 0; r < 8; ++r) {
      int rg = r >> 1, ks = r & 1;
      const ushort* g = gc + ((((size_t)(rgbase + rg)) * 2 + ks) * 64 + l) * 8;
      ushort* s = lbuf + ((rg * 2 + ks) * 64 + l) * 8;
      gll16(g, s);
    }
  }
  __syncthreads();
  f32x16 wacc[2][2];
  wacc[0][0] = zero16; wacc[0][1] = zero16; wacc[1][0] = zero16; wacc[1][1] = zero16;
  #pragma unroll
  for (int ks = 0; ks < 2; ++ks) {
    bf16x8 caH[2], caL[2], cbH[2], cbL[2];
    #pragma unroll
    for (int rg = 0; rg < 2; ++rg) {
      int o = (((wrg + rg) * 2 + ks) * 64 + l) * 8;
      caH[rg] = *(const bf16x8*)(As[0] + o);
      caL[rg] = *(const bf16x8*)(As[1] + o);
      int o2 = (((wcg + rg) * 2 + ks) * 64 + l) * 8;
      cbH[rg] = *(const bf16x8*)(Bs[0] + o2);
      cbL[rg] = *(const bf16x8*)(Bs[1] + o2);
    }
    #pragma unroll
    for (int i = 0; i < 2; ++i)
      #pragma unroll
      for (int j = 0; j < 2; ++j) {
        wacc[i][j] = __builtin_amdgcn_mfma_f32_32x32x16_bf16(caH[i], cbH[j], wacc[i][j], 0, 0, 0);
        wacc[i][j] = __builtin_amdgcn_mfma_f32_32x32x16_bf16(caH[i], cbL[j], wacc[i][j], 0, 0, 0);
        wacc[i][j] = __builtin_amdgcn_mfma_f32_32x32x16_bf16(caL[i], cbH[j], wacc[i][j], 0, 0, 0);
      }
  }

  // epilogue: L2 -> 5-scale gaussian -> weighted partial sum
  float nib = scal[0], invlen = scal[1];
  float partial = 0.f;
  int colb = (wid & 1) * 64 + (l & 31);
  int rowb = (wid >> 1) * 64 + 4 * (l >> 5);
  #pragma unroll
  for (int i = 0; i < 2; ++i)
    #pragma unroll
    for (int j = 0; j < 2; ++j) {
      float sb = sqB[colb + j * 32];
      #pragma unroll
      for (int reg = 0; reg < 16; ++reg) {
        int row = rowb + i * 32 + (reg & 3) + 8 * (reg >> 2);
        float l2 = fmaxf(sqA[row] + sb - 2.0f * acc[i][j][reg], 0.f);
        float g = l2 * nib;
        float kern = __expf(g) + __expf(g * 0.5f) + __expf(g * 0.25f)
                   + __expf(g * 0.125f) + __expf(g * 0.0625f);
        partial = fmaf(wacc[i][j][reg], kern, partial);
      }
    }
  #pragma unroll
  for (int off = 32; off; off >>= 1) partial += __shfl_xor(partial, off);
  if (l == 0) red[wid] = partial;
  __syncthreads();
  if (tid == 0) {
    float v = (red[0] + red[1] + red[2] + red[3]) * invlen * ((ti == tj) ? 1.0f : 2.0f);
    atomicAdd(out, v);
  }
}

extern "C" void kernel_launch(void* const* d_in, const int* in_sizes, int n_in,
                              void* d_out, int out_size, void* d_ws, size_t ws_size,
                              hipStream_t stream) {
  const float* src = (const float*)d_in[0];
  const float* tgt = (const float*)d_in[1];
  const int* slab  = (const int*)d_in[2];
  const float* tl  = (const float*)d_in[3];
  float* out = (float*)d_out;

  ushort* hiG = (ushort*)d_ws;           // 8192*512 ushorts
  ushort* loG = hiG + 4194304;
  ushort* cH  = loG + 4194304;           // 8192*32
  ushort* cL  = cH + 262144;
  float* fb   = (float*)(cL + 262144);
  float* sq     = fb;            // 8192
  float* m      = fb + 8192;     // 512
  float* tsum   = fb + 8704;     // 32
  int*   pres   = (int*)(fb + 8736);  // 32
  float* sval   = fb + 8768;     // 32
  float* tscale = fb + 8800;     // 32
  float* scal   = fb + 8832;     // 2

  hipMemsetAsync(out, 0, sizeof(float), stream);
  hipMemsetAsync(m, 0, 576 * sizeof(float), stream);

  hipLaunchKernelGGL(k_split,  dim3(4096), dim3(256), 0, stream, src, tgt, hiG, loG);
  hipLaunchKernelGGL(k_row_sq, dim3(2048), dim3(256), 0, stream, src, tgt, sq);
  hipLaunchKernelGGL(k_colsum, dim3(64),   dim3(256), 0, stream, src, tgt, m);
  hipLaunchKernelGGL(k_tstats, dim3(32),   dim3(256), 0, stream, tl, tsum, pres);
  hipLaunchKernelGGL(k_prep,   dim3(1),    dim3(256), 0, stream, sq, m, slab, tsum, pres, sval, tscale, scal);
  hipLaunchKernelGGL(k_cvec,   dim3(32),   dim3(256), 0, stream, slab, tl, sval, tscale, cH, cL);
  hipLaunchKernelGGL(k_main,   dim3(2080), dim3(256), 0, stream, hiG, loG, cH, cL, sq, scal, out);
}